// Round 3
// baseline (520.137 us; speedup 1.0000x reference)
//
#include <hip/hip_runtime.h>
#include <hip/hip_bf16.h>

// TinyLocalWindowAttention on MI355X (gfx950)
// x:(32,256,112,112) f32, 7x7 windows, 8192 windows; 1 block (4 waves) per window.
// bf16 MFMA 16x16x32 throughout. LDS 40KB -> 4 blocks/CU.
// Softmax: no-max (data-safe), row-sums via ones-MFMA, deferred normalization.

typedef short bf16x8 __attribute__((ext_vector_type(8)));   // 8 bf16 (4 VGPRs)
typedef float f32x4 __attribute__((ext_vector_type(4)));

static __device__ __forceinline__ unsigned short cvt1(float f) {
    __hip_bfloat16 h = __float2bfloat16(f);
    unsigned short u; __builtin_memcpy(&u, &h, 2); return u;
}
static __device__ __forceinline__ unsigned int cvt2(float a, float b) {
    float2 t; t.x = a; t.y = b;
    __hip_bfloat162 h = __float22bfloat162_rn(t);
    unsigned int u; __builtin_memcpy(&u, &h, 4); return u;
}
static __device__ __forceinline__ float bf2f(unsigned int hs) {
    return __uint_as_float(hs << 16);
}

#define PROJ_OFF 65536   // bf16 elems offset of proj frags in ws

// ---- pre-pass: Wqkv[256][256], Wproj[128][256] f32 -> bf16 B-fragment arrays ----
__global__ void prep_weights(const float* __restrict__ Wqkv,
                             const float* __restrict__ Wproj,
                             unsigned short* __restrict__ ws) {
    int tid = blockIdx.x * 256 + threadIdx.x;
    if (tid < 8192) {                         // 16 ntiles * 8 ktiles * 64 lanes
        int lane = tid & 63, f = tid >> 6;
        int kt = f & 7, nt = f >> 3;
        int kbase = kt * 32 + (lane >> 4) * 8;
        int col = nt * 16 + (lane & 15);
        uint4 u;
        u.x = cvt2(Wqkv[(kbase + 0) * 256 + col], Wqkv[(kbase + 1) * 256 + col]);
        u.y = cvt2(Wqkv[(kbase + 2) * 256 + col], Wqkv[(kbase + 3) * 256 + col]);
        u.z = cvt2(Wqkv[(kbase + 4) * 256 + col], Wqkv[(kbase + 5) * 256 + col]);
        u.w = cvt2(Wqkv[(kbase + 6) * 256 + col], Wqkv[(kbase + 7) * 256 + col]);
        *reinterpret_cast<uint4*>(&ws[tid * 8]) = u;
    } else if (tid < 12288) {                 // 16 ntiles * 4 ktiles * 64 lanes
        int i2 = tid - 8192;
        int lane = i2 & 63, f = i2 >> 6;
        int kt = f & 3, nt = f >> 2;
        int kbase = kt * 32 + (lane >> 4) * 8;
        int col = nt * 16 + (lane & 15);
        uint4 u;
        u.x = cvt2(Wproj[(kbase + 0) * 256 + col], Wproj[(kbase + 1) * 256 + col]);
        u.y = cvt2(Wproj[(kbase + 2) * 256 + col], Wproj[(kbase + 3) * 256 + col]);
        u.z = cvt2(Wproj[(kbase + 4) * 256 + col], Wproj[(kbase + 5) * 256 + col]);
        u.w = cvt2(Wproj[(kbase + 6) * 256 + col], Wproj[(kbase + 7) * 256 + col]);
        *reinterpret_cast<uint4*>(&ws[PROJ_OFF + i2 * 8]) = u;
    }
}

// LDS (40 KB total -> 4 blocks/CU):
//  A [32KB, 16384 elems]:
//    xa[64][256] -> { q[64][64]@0, k[64][64]@4096, vT[4][32][64]@8192 }
//    -> o_s[64][128]@0 (over q+k, after PV barrier) -> out_s[64][256] (everything)
//  P [8KB, 4096 elems]: per-head quarter buffer p[16][64] at h*1024 (wave-private)
// swizzle: elem(row,col,W) = row*W + (((col>>3) ^ (row&7))<<3) + (col&7)

__global__ __launch_bounds__(256, 4) void win_attn(
    const float* __restrict__ x,
    const unsigned short* __restrict__ wf,
    const float* __restrict__ bqkv,
    const float* __restrict__ bproj,
    float* __restrict__ out)
{
    __shared__ __align__(16) unsigned short A[16384];
    __shared__ __align__(16) unsigned short Pb[4096];

    const int tid  = threadIdx.x;
    const int lane = tid & 63;
    const int wave = tid >> 6;
    const int lr   = lane & 15;       // row/col within 16-tile
    const int kg   = lane >> 4;       // k-group (0..3)

    // XCD swizzle: contiguous 1024 windows per XCD
    const int bid = (int)blockIdx.x;
    const int L   = (bid & 7) * 1024 + (bid >> 3);
    const int b   = L >> 8;
    const int rem = L & 255;
    const int h0 = (rem >> 4) * 7;
    const int w0 = (rem & 15) * 7;
    const int xwin = (b * 256) * 12544 + h0 * 112 + w0;

    // preload biases
    float bqv[4], bpv[4];
    #pragma unroll
    for (int nn = 0; nn < 4; ++nn) {
        bqv[nn] = bqkv[wave * 64 + nn * 16 + lr];
        bpv[nn] = bproj[wave * 64 + nn * 16 + lr];
    }

    // ---- phase A: zero pad rows 49..63, load x window -> xa (bf16) ----
    for (int i = tid; i < 15 * 128; i += 256)
        reinterpret_cast<unsigned int*>(A)[49 * 128 + i] = 0u;

    if (lane < 49) {
        const int lb = xwin + (lane / 7) * 112 + (lane % 7);
        #pragma unroll 4
        for (int it = 0; it < 16; ++it) {
            const int c0 = wave * 64 + it * 4;
            const float v0 = x[lb + (c0 + 0) * 12544];
            const float v1 = x[lb + (c0 + 1) * 12544];
            const float v2 = x[lb + (c0 + 2) * 12544];
            const float v3 = x[lb + (c0 + 3) * 12544];
            uint2 pk; pk.x = cvt2(v0, v1); pk.y = cvt2(v2, v3);
            const int e = lane * 256 + (((c0 >> 3) ^ (lane & 7)) << 3) + (c0 & 7);
            *reinterpret_cast<uint2*>(&A[e]) = pk;
        }
    }
    __syncthreads();   // (1) xa ready

    // ---- phase B: qkv = xa @ Wqkv ; wave w owns output cols [64w, 64w+64) ----
    f32x4 acc[4][4];
    #pragma unroll
    for (int m = 0; m < 4; ++m)
        #pragma unroll
        for (int nn = 0; nn < 4; ++nn)
            acc[m][nn] = f32x4{0.f, 0.f, 0.f, 0.f};

    #pragma unroll
    for (int kt = 0; kt < 8; ++kt) {
        bf16x8 a[4], bw[4];
        #pragma unroll
        for (int m = 0; m < 4; ++m) {
            const int row = lr + 16 * m;
            const int ch  = (kt * 4 + kg) ^ (row & 7);
            a[m] = *reinterpret_cast<const bf16x8*>(&A[row * 256 + ch * 8]);
        }
        #pragma unroll
        for (int nn = 0; nn < 4; ++nn) {
            const int nt = wave * 4 + nn;
            bw[nn] = *reinterpret_cast<const bf16x8*>(&wf[((nt * 8 + kt) * 64 + lane) * 8]);
        }
        #pragma unroll
        for (int m = 0; m < 4; ++m)
            #pragma unroll
            for (int nn = 0; nn < 4; ++nn)
                acc[m][nn] = __builtin_amdgcn_mfma_f32_16x16x32_bf16(a[m], bw[nn], acc[m][nn], 0, 0, 0);
    }
    __syncthreads();   // (2) all waves done READING xa (q/k/vT overlay it)

    // epilogue: +bias; wave0 -> q@A[0), wave1 -> k@A[4096), waves 2,3 -> vT@A[8192)
    #pragma unroll
    for (int nn = 0; nn < 4; ++nn) {
        const int colg = wave * 64 + nn * 16 + lr;
        #pragma unroll
        for (int m = 0; m < 4; ++m)
            #pragma unroll
            for (int r = 0; r < 4; ++r) {
                const int row = kg * 4 + r + 16 * m;        // token
                const unsigned short hv = cvt1(acc[m][nn][r] + bqv[nn]);
                if (wave < 2) {
                    const int c = colg & 63;
                    A[(wave << 12) + row * 64 + (((c >> 3) ^ (row & 7)) << 3) + (c & 7)] = hv;
                } else {
                    const int vc = colg - 128;
                    const int hh = vc >> 5, d = vc & 31;
                    A[8192 + hh * 2048 + d * 64 + (((row >> 3) ^ (d & 7)) << 3) + (row & 7)] = hv;
                }
            }
    }
    __syncthreads();   // (3) q/k/vT ready

    // ---- attention, head h = wave ----
    const int h = wave;

    // hoist K fragments (B-operand of S) and V fragments (B-operand of PV)
    bf16x8 kf[4], vb[2][2];
    const bf16x8 zf = {0, 0, 0, 0, 0, 0, 0, 0};
    #pragma unroll
    for (int nt = 0; nt < 4; ++nt) {
        if (lane < 32) {
            const int row = lr + 16 * nt;               // k-token
            kf[nt] = *reinterpret_cast<const bf16x8*>(
                &A[4096 + row * 64 + (((h * 2 + kg) ^ (row & 7)) << 3)]);
        } else kf[nt] = zf;
    }
    #pragma unroll
    for (int kt = 0; kt < 2; ++kt)
        #pragma unroll
        for (int nt = 0; nt < 2; ++nt) {
            const int d = lr + 16 * nt;
            const int ch = (kt * 4 + kg) ^ (d & 7);
            vb[kt][nt] = *reinterpret_cast<const bf16x8*>(&A[8192 + h * 2048 + d * 64 + ch * 8]);
        }
    const bf16x8 ones = {(short)16256, (short)16256, (short)16256, (short)16256,
                         (short)16256, (short)16256, (short)16256, (short)16256};

    // per-quarter: S m-tile -> exp (no max) -> p[16][64] -> PV + ones-MFMA row sums
    f32x4 oacc[4][2], sacc[4];
    #pragma unroll
    for (int m = 0; m < 4; ++m) {
        oacc[m][0] = f32x4{0.f, 0.f, 0.f, 0.f};
        oacc[m][1] = f32x4{0.f, 0.f, 0.f, 0.f};
        sacc[m]    = f32x4{0.f, 0.f, 0.f, 0.f};
    }
    const bool v3 = (lr == 0);              // in nt==3 only col 48 is valid
    const float C = 0.25f * 1.44269504f;    // SCALE * log2(e)

    #pragma unroll
    for (int m = 0; m < 4; ++m) {
        // S m-tile: q rows [16m,16m+16) x all 64 k-tokens
        bf16x8 qf;
        if (lane < 32) {
            const int row = lr + 16 * m;
            qf = *reinterpret_cast<const bf16x8*>(
                &A[row * 64 + (((h * 2 + kg) ^ (row & 7)) << 3)]);
        } else qf = zf;

        f32x4 s[4];
        #pragma unroll
        for (int nt = 0; nt < 4; ++nt) {
            f32x4 z = f32x4{0.f, 0.f, 0.f, 0.f};
            s[nt] = __builtin_amdgcn_mfma_f32_16x16x32_bf16(qf, kf[nt], z, 0, 0, 0);
        }

        // exp2(s*C), zero invalid cols, write p (wave-private, no barrier)
        #pragma unroll
        for (int nt = 0; nt < 4; ++nt)
            #pragma unroll
            for (int r = 0; r < 4; ++r) {
                const float e = (nt == 3 && !v3) ? 0.f : __builtin_amdgcn_exp2f(s[nt][r] * C);
                const int rw = kg * 4 + r;
                const int col = lr + 16 * nt;
                Pb[h * 1024 + rw * 64 + (((col >> 3) ^ (rw & 7)) << 3) + (col & 7)] = cvt1(e);
            }

        // PV quarter: rows = lr (16), K = 64 tokens
        #pragma unroll
        for (int kt = 0; kt < 2; ++kt) {
            const int ch = (kt * 4 + kg) ^ (lr & 7);
            const bf16x8 pa = *reinterpret_cast<const bf16x8*>(&Pb[h * 1024 + lr * 64 + ch * 8]);
            oacc[m][0] = __builtin_amdgcn_mfma_f32_16x16x32_bf16(pa, vb[kt][0], oacc[m][0], 0, 0, 0);
            oacc[m][1] = __builtin_amdgcn_mfma_f32_16x16x32_bf16(pa, vb[kt][1], oacc[m][1], 0, 0, 0);
            sacc[m]    = __builtin_amdgcn_mfma_f32_16x16x32_bf16(pa, ones,      sacc[m],    0, 0, 0);
        }
    }

    __syncthreads();   // (4) q/k dead for ALL waves -> o_s overlays A[0..8192)

    // normalize by row sums and write o_s[64][128] @ A[0)
    #pragma unroll
    for (int m = 0; m < 4; ++m) {
        f32x4 rs;
        #pragma unroll
        for (int r = 0; r < 4; ++r) rs[r] = __builtin_amdgcn_rcpf(sacc[m][r]);
        #pragma unroll
        for (int nt = 0; nt < 2; ++nt)
            #pragma unroll
            for (int r = 0; r < 4; ++r) {
                const int row = kg * 4 + r + 16 * m;
                const int col = h * 32 + nt * 16 + lr;
                A[row * 128 + (((col >> 3) ^ (row & 7)) << 3) + (col & 7)] =
                    cvt1(oacc[m][nt][r] * rs[r]);
            }
    }
    __syncthreads();   // (5) o_s ready

    // ---- proj: out = o_s @ Wproj + bproj ----
    f32x4 pc[4][4];
    #pragma unroll
    for (int m = 0; m < 4; ++m)
        #pragma unroll
        for (int nn = 0; nn < 4; ++nn)
            pc[m][nn] = f32x4{0.f, 0.f, 0.f, 0.f};

    #pragma unroll
    for (int kt = 0; kt < 4; ++kt) {
        bf16x8 a[4], bw[4];
        #pragma unroll
        for (int m = 0; m < 4; ++m) {
            const int row = lr + 16 * m;
            const int ch = (kt * 4 + kg) ^ (row & 7);
            a[m] = *reinterpret_cast<const bf16x8*>(&A[row * 128 + ch * 8]);
        }
        #pragma unroll
        for (int nn = 0; nn < 4; ++nn) {
            const int nt = wave * 4 + nn;
            bw[nn] = *reinterpret_cast<const bf16x8*>(&wf[PROJ_OFF + ((nt * 4 + kt) * 64 + lane) * 8]);
        }
        #pragma unroll
        for (int m = 0; m < 4; ++m)
            #pragma unroll
            for (int nn = 0; nn < 4; ++nn)
                pc[m][nn] = __builtin_amdgcn_mfma_f32_16x16x32_bf16(a[m], bw[nn], pc[m][nn], 0, 0, 0);
    }
    __syncthreads();   // (6) proj reads done -> out_s overlays everything

    // write out_s[64][256] into A
    #pragma unroll
    for (int nn = 0; nn < 4; ++nn) {
        const int colg = wave * 64 + nn * 16 + lr;
        #pragma unroll
        for (int m = 0; m < 4; ++m)
            #pragma unroll
            for (int r = 0; r < 4; ++r) {
                const int row = kg * 4 + r + 16 * m;
                A[row * 256 + (((colg >> 3) ^ (row & 7)) << 3) + (colg & 7)] = cvt1(pc[m][nn][r] + bpv[nn]);
            }
    }
    // no barrier: each wave re-reads only its own column range below
    __builtin_amdgcn_wave_barrier();

    // ---- store: same 7-contiguous-float pattern as the loads (wave-own cols) ----
    if (lane < 49) {
        const int lb = xwin + (lane / 7) * 112 + (lane % 7);
        #pragma unroll 4
        for (int it = 0; it < 16; ++it) {
            const int c0 = wave * 64 + it * 4;
            const int e = lane * 256 + (((c0 >> 3) ^ (lane & 7)) << 3) + (c0 & 7);
            const uint2 pk = *reinterpret_cast<const uint2*>(&A[e]);
            out[lb + (c0 + 0) * 12544] = bf2f(pk.x & 0xffffu);
            out[lb + (c0 + 1) * 12544] = bf2f(pk.x >> 16);
            out[lb + (c0 + 2) * 12544] = bf2f(pk.y & 0xffffu);
            out[lb + (c0 + 3) * 12544] = bf2f(pk.y >> 16);
        }
    }
}

extern "C" void kernel_launch(void* const* d_in, const int* in_sizes, int n_in,
                              void* d_out, int out_size, void* d_ws, size_t ws_size,
                              hipStream_t stream) {
    const float* x     = (const float*)d_in[0];
    const float* Wqkv  = (const float*)d_in[1];
    const float* bqkv  = (const float*)d_in[2];
    const float* Wproj = (const float*)d_in[3];
    const float* bproj = (const float*)d_in[4];
    unsigned short* wf = (unsigned short*)d_ws;   // 192 KB used

    prep_weights<<<48, 256, 0, stream>>>(Wqkv, Wproj, wf);
    win_attn<<<8192, 256, 0, stream>>>(x, wf, bqkv, bproj, (float*)d_out);
}